// Round 11
// baseline (271.908 us; speedup 1.0000x reference)
//
#include <hip/hip_runtime.h>
#include <hip/hip_bf16.h>
#include <math.h>

typedef _Float16 half2_t __attribute__((ext_vector_type(2)));
typedef _Float16 f16x8   __attribute__((ext_vector_type(8)));
typedef float    f32x4   __attribute__((ext_vector_type(4)));

constexpr int BATCH = 32768;
constexpr int NI   = 32;
constexpr int OWND = 3;
constexpr int INTD = 7;
constexpr int AD   = 128;
constexpr int HIDN = 256;
constexpr int OUTD = 2;
constexpr int OBSD = OWND + NI * INTD;  // 227
constexpr int IEPITCH = 68;             // uints (=136 halves)
constexpr float C2L2E = 2.885390081777927f;   // 2*log2(e)

__device__ __forceinline__ half2_t u2h(unsigned u) { return __builtin_bit_cast(half2_t, u); }
__device__ __forceinline__ unsigned packf(float a, float b) {
    half2_t h = { (_Float16)a, (_Float16)b };
    return __builtin_bit_cast(unsigned, h);
}
// slope<1 => lrelu(x) == max(x, 0.2x): 2 VALU (mul+max).
__device__ __forceinline__ float lrelu(float x) { return fmaxf(x, 0.2f * x); }
// hardware v_exp_f32 is 2^x; __builtin_amdgcn_exp2f is the portable spelling.
__device__ __forceinline__ float exp2fast(float x) { return __builtin_amdgcn_exp2f(x); }
// tanh via native exp2 + rcp.
__device__ __forceinline__ float fast_tanh(float x) {
    float e = exp2fast(x * C2L2E);
    return 1.0f - 2.0f * __builtin_amdgcn_rcpf(e + 1.0f);
}

// ===================== ws layout (uints) =====================
constexpr int UW_PWKQ = 0;        // [Wk;Wq] B-frags (f=kt*8+nt, kt<8; kt<4=Wk, kt>=4=Wq): 16384
constexpr int UW_PWVF = 16384;    // Wv B-frags (kt<4): 8192
constexpr int UW_PPRF = 24576;    // proj B-frags: 8192
constexpr int UW_PIWF = 32768;    // int_W K=32-padded B-frags (f=nt), bias fused at k=7: 2048
constexpr int UW_PH1F = 34816;    // h1 B-frags (f=nt*8+kt): 32768
constexpr int UW_PH2F = 67584;    // h2 B-frags: 32768
constexpr int UW_FULL = 100352;   // 392 KB
constexpr size_t XBUF_U = (size_t)BATCH * (HIDN / 2);  // 16 MB

__global__ __launch_bounds__(256) void pack_full(
    const float* __restrict__ Wq, const float* __restrict__ Wk,
    const float* __restrict__ Wv, const float* __restrict__ Pr,
    const float* __restrict__ IW, const float* __restrict__ IB,
    const float* __restrict__ H1, const float* __restrict__ H2,
    unsigned* __restrict__ dst)
{
    int u = blockIdx.x * 256 + threadIdx.x;
    if (u >= UW_FULL) return;
    if (u < 16384) {                       // [Wk;Wq] stacked B-frags (K=256)
        int f = u >> 8, kt = f >> 3, nt = f & 7;
        int idx = u & 255, lane = idx >> 2, w = idx & 3;
        int qd = lane >> 4, lo = lane & 15;
        const float* src = (kt < 4) ? Wk : Wq;
        int ktp = kt & 3;
        int r0 = 32 * ktp + 8 * qd + 2 * w, col = 16 * nt + lo;
        dst[u] = packf(src[r0 * 128 + col], src[(r0 + 1) * 128 + col]);
    } else if (u < 32768) {                // Wv / proj B-frags (128x128)
        const float* src = (u < 24576) ? Wv : Pr;
        int i = (u - 16384) & 8191;
        int f = i >> 8, kt = f >> 3, nt = f & 7;
        int idx = i & 255, lane = idx >> 2, w = idx & 3;
        int qd = lane >> 4, lo = lane & 15;
        int r0 = 32 * kt + 8 * qd + 2 * w, col = 16 * nt + lo;
        dst[u] = packf(src[r0 * 128 + col], src[(r0 + 1) * 128 + col]);
    } else if (u < 34816) {                // int_W (7x128) K=32-pad; k=7 row = int_b
        int i = u - 32768;
        int nt = i >> 8;
        int idx = i & 255, lane = idx >> 2, w = idx & 3;
        int qd = lane >> 4, lo = lane & 15;
        int r0 = 8 * qd + 2 * w, col = 16 * nt + lo;
        float v0 = (r0 < INTD) ? IW[r0 * 128 + col] : 0.f;       // r0 even, never ==7
        float v1 = (r0 + 1 < INTD) ? IW[(r0 + 1) * 128 + col]
                 : ((r0 + 1 == INTD) ? IB[col] : 0.f);
        dst[u] = packf(v0, v1);
    } else {                               // H1/H2 B-frags (256x256)
        int i = u - 34816;
        const float* src = (i < 32768) ? H1 : H2;
        i &= 32767;
        int f = i >> 8, nt = f >> 3, kt = f & 7;
        int idx = i & 255, lane = idx >> 2, w = idx & 3;
        int qd = lane >> 4, lo = lane & 15;
        int r0 = 32 * kt + 8 * qd + 2 * w, col = 16 * nt + lo;
        dst[u] = packf(src[r0 * 256 + col], src[(r0 + 1) * 256 + col]);
    }
}

// ---- attention v9: qgemm fused via REPLICATED-A q-MFMA, zero barriers.
// R10's cross-wave q sharing added 2 barriers + bank-conflicted s_ownh
// reads (conflicts 1.05M->2.62M) and cost 11us. Fix: build the q A-frag
// as own_e replicated across all 16 M-rows (A[row][k]=own_e[k], read from
// s_ownh[wv] — wave-private, lockstep-ordered, conflict-free broadcast).
// Every C row then equals q, so each lane reads q[16nt+lo] from acc[0]
// directly: no s_q, no barriers, no cross-wave dependency. +32 MFMA and
// +32 L2-hit loads per wave (~2-4us chip) buys back the barrier and
// conflict cost. q math bitwise-identical to the old qgemm (same own_e
// rounding, same fragment accumulation order).
__global__ __launch_bounds__(256) void attn(
    const float* __restrict__ obs,
    const float* __restrict__ own_W, const float* __restrict__ own_b,
    const unsigned* __restrict__ pIWF,
    const unsigned* __restrict__ pWkqF, const float* __restrict__ v_att,
    unsigned* __restrict__ xbuf)
{
    const int wv = threadIdx.x >> 6;         // wave 0..3 -> row
    const int l  = threadIdx.x & 63;
    const int b  = blockIdx.x * 4 + wv;
    const int d0 = 2 * l;
    const int lo = l & 15, qd = l >> 4;

    __shared__ __align__(16) float    s_obs[4][OBSD];
    __shared__ __align__(16) unsigned s_ieb[4][NI * IEPITCH];  // int_e halves, swizzled
    __shared__ __align__(16) unsigned s_ownh[4][AD / 2];
    __shared__ __align__(16) float    s_sc[4][NI];             // scores, reused as alpha

    const float* orow = obs + (size_t)b * OBSD;
    for (int i = l; i < OBSD; i += 64) s_obs[wv][i] = orow[i];

    float oe0 = own_b[d0], oe1 = own_b[d0 + 1];
    #pragma unroll
    for (int j = 0; j < OWND; j++) {
        float x = s_obs[wv][j];
        oe0 += x * own_W[j * AD + d0];
        oe1 += x * own_W[j * AD + d0 + 1];
    }
    oe0 = lrelu(oe0); oe1 = lrelu(oe1);
    s_ownh[wv][l] = packf(oe0, oe1);

    int padf = 0;
    if (l < NI) {
        float su = 0.f;
        #pragma unroll
        for (int j = 0; j < INTD; j++) su += fabsf(s_obs[wv][OWND + l * INTD + j]);
        padf = (su < 1e-6f);
    }

    // ---- per-wave q = own_e @ Wq with replicated-A (no barrier, no LDS out).
    // aQ[kt][j] = own_e[32kt + 8qd + j] for ALL lanes -> every C row = q.
    // qe[nt] = acc[0] = q[16nt+lo], pre-scaled for the exp2 tanh chain.
    float qe[8];
    {
        f16x8 aQ[4];
        #pragma unroll
        for (int kt = 0; kt < 4; kt++) {
            // s_ownh[wv] written by this wave above; same-wave LDS ordering.
            // 4 distinct 16B addrs (banks 4qd..) -> broadcast, conflict-free.
            uint4 au = *(const uint4*)(&s_ownh[wv][16 * kt + 4 * qd]);
            aQ[kt] = __builtin_bit_cast(f16x8, au);
        }
        #pragma unroll
        for (int nt = 0; nt < 8; nt++) {
            f32x4 acc = {0.f, 0.f, 0.f, 0.f};
            #pragma unroll
            for (int kt = 0; kt < 4; kt++) {   // Wq lives at kt 4..7 of the stack
                uint4 bu = *(const uint4*)(pWkqF + (((kt + 4) * 8 + nt) << 8) + (l << 2));
                acc = __builtin_amdgcn_mfma_f32_16x16x32_f16(aQ[kt], __builtin_bit_cast(f16x8, bu), acc, 0, 0, 0);
            }
            qe[nt] = acc[0] * C2L2E;
        }
    }

    // ---- int_e via MFMA; k=7 supplies 1.0 (bias row fused in IWF) ----
    f16x8 aInt[2];
    #pragma unroll
    for (int t = 0; t < 2; t++) {
        #pragma unroll
        for (int j = 0; j < 8; j++) {
            int k = 8 * qd + j;
            float v;
            if (k < INTD)       v = s_obs[wv][OWND + (16 * t + lo) * INTD + k];
            else if (k == INTD) v = 1.0f;
            else                v = 0.f;
            aInt[t][j] = (_Float16)v;
        }
    }
    // swizzled store: half-index col' = (16nt+lo) ^ (qd<<3)
    _Float16* s_ieh = (_Float16*)s_ieb[wv];
    #pragma unroll
    for (int nt = 0; nt < 8; nt++) {
        uint4 bu = *(const uint4*)(pIWF + (nt << 8) + (l << 2));
        f16x8 bf = __builtin_bit_cast(f16x8, bu);
        f32x4 z = {0.f, 0.f, 0.f, 0.f};
        f32x4 c0 = __builtin_amdgcn_mfma_f32_16x16x32_f16(aInt[0], bf, z, 0, 0, 0);
        f32x4 c1 = __builtin_amdgcn_mfma_f32_16x16x32_f16(aInt[1], bf, z, 0, 0, 0);
        const int cswz = (16 * nt + lo) ^ (qd << 3);
        #pragma unroll
        for (int r = 0; r < 4; r++) {
            s_ieh[(4 * qd + r) * 136 + cswz]      = (_Float16)lrelu(c0[r]);
            s_ieh[(16 + 4 * qd + r) * 136 + cswz] = (_Float16)lrelu(c1[r]);
        }
    }

    // ---- A-frags (swizzled read) ----
    const int slo = ((lo >> 2) & 3) << 2;
    f16x8 aIE[2][4];
    #pragma unroll
    for (int t = 0; t < 2; t++)
        #pragma unroll
        for (int kt = 0; kt < 4; kt++) {
            uint4 au = *(const uint4*)(&s_ieb[wv][(16 * t + lo) * IEPITCH + ((16 * kt + 4 * qd) ^ slo)]);
            aIE[t][kt] = __builtin_bit_cast(f16x8, au);
        }

    // ---- k MFMA + fused tanh-score partials ----
    float sA0[4] = {0.f, 0.f, 0.f, 0.f};
    float sA1[4] = {0.f, 0.f, 0.f, 0.f};
    float vsum = 0.f;
    #pragma unroll
    for (int nt = 0; nt < 8; nt++) {
        f32x4 acc0 = {0.f, 0.f, 0.f, 0.f};
        f32x4 acc1 = {0.f, 0.f, 0.f, 0.f};
        #pragma unroll
        for (int kt = 0; kt < 4; kt++) {
            uint4 bu = *(const uint4*)(pWkqF + ((kt * 8 + nt) << 8) + (l << 2));
            f16x8 bf = __builtin_bit_cast(f16x8, bu);
            acc0 = __builtin_amdgcn_mfma_f32_16x16x32_f16(aIE[0][kt], bf, acc0, 0, 0, 0);
            acc1 = __builtin_amdgcn_mfma_f32_16x16x32_f16(aIE[1][kt], bf, acc1, 0, 0, 0);
        }
        const float vc   = v_att[16 * nt + lo];
        const float n2vc = -2.0f * vc;
        vsum += vc;
        #pragma unroll
        for (int r = 0; r < 4; r++) {
            float t0 = exp2fast(fmaf(acc0[r], C2L2E, qe[nt]));
            sA0[r] = fmaf(n2vc, __builtin_amdgcn_rcpf(t0 + 1.0f), sA0[r]);
            float t1 = exp2fast(fmaf(acc1[r], C2L2E, qe[nt]));
            sA1[r] = fmaf(n2vc, __builtin_amdgcn_rcpf(t1 + 1.0f), sA1[r]);
        }
    }
    #pragma unroll
    for (int r = 0; r < 4; r++) { sA0[r] += vsum; sA1[r] += vsum; }
    #pragma unroll
    for (int r = 0; r < 4; r++) {
        #pragma unroll
        for (int w = 1; w <= 8; w <<= 1) {
            sA0[r] += __shfl_xor(sA0[r], w, 64);
            sA1[r] += __shfl_xor(sA1[r], w, 64);
        }
    }
    if (lo == 0) {
        #pragma unroll
        for (int r = 0; r < 4; r++) {
            s_sc[wv][4 * qd + r]      = sA0[r];
            s_sc[wv][16 + 4 * qd + r] = sA1[r];
        }
    }

    // ---- softmax ----
    {
        float sval = -INFINITY;
        if (l < NI && !padf) sval = s_sc[wv][l];
        float mm = sval;
        #pragma unroll
        for (int w = 1; w <= 16; w <<= 1) mm = fmaxf(mm, __shfl_xor(mm, w, 64));
        float e = (sval > -INFINITY) ? __expf(sval - mm) : 0.f;
        float dd = e;
        #pragma unroll
        for (int w = 1; w <= 16; w <<= 1) dd += __shfl_xor(dd, w, 64);
        if (l < NI) s_sc[wv][l] = (dd > 0.f) ? e * __builtin_amdgcn_rcpf(dd) : 0.f;  // nan_to_num
    }

    // ---- sv = alpha @ int_e ----
    float sv0 = 0.f, sv1 = 0.f;
    #pragma unroll
    for (int n = 0; n < NI; n++) {
        const int sn = ((n >> 2) & 3) << 2;
        half2_t ie = u2h(s_ieb[wv][n * IEPITCH + (l ^ sn)]);
        float a = s_sc[wv][n];
        sv0 += a * (float)ie.x; sv1 += a * (float)ie.y;
    }
    xbuf[(size_t)b * (HIDN / 2) + l]      = s_ownh[wv][l];
    xbuf[(size_t)b * (HIDN / 2) + 64 + l] = packf(sv0, sv1);
}

// ---- mlp8w: 32-row tiles, EIGHT waves (unchanged — best so far) ----
__global__ __launch_bounds__(512) void mlp8w(
    const unsigned* __restrict__ xbuf,
    const unsigned* __restrict__ pWvF, const float* __restrict__ proj_b,
    const unsigned* __restrict__ pPrF,
    const unsigned* __restrict__ pH1F, const float* __restrict__ h1_b,
    const unsigned* __restrict__ pH2F, const float* __restrict__ h2_b,
    const float* __restrict__ out_W,   const float* __restrict__ out_b,
    float* __restrict__ res)
{
    const int tid = threadIdx.x;
    const int wv  = tid >> 6;          // wave 0..7
    const int l   = tid & 63;
    const int lo  = l & 15, qd = l >> 4;
    const size_t row0 = (size_t)blockIdx.x * 32;

    __shared__ __align__(16) unsigned s_x[32 * 132];    // own_e | attn_vec -> h1 (in place)
    __shared__ __align__(16) unsigned s_scr[32 * 68];   // sv -> ctx (in place)
    __shared__ __align__(16) float    s_red[8][32][2];

    #pragma unroll
    for (int it = 0; it < 2; it++) {
        int i = tid + it * 512;
        int r = i >> 5, cq = i & 31;
        uint4 u = *(const uint4*)(xbuf + (row0 + r) * 128 + cq * 4);
        if (cq < 16) *(uint4*)(&s_x[r * 132 + cq * 4]) = u;
        else         *(uint4*)(&s_scr[r * 68 + (cq - 16) * 4]) = u;
    }
    __syncthreads();

    _Float16* s_ctxh = (_Float16*)s_scr;
    _Float16* s_xh   = (_Float16*)s_x;

    // ---- stage 1: ctx = sv @ Wv ; wave owns nt = wv ----
    #pragma unroll
    for (int rowg = 0; rowg < 2; rowg++) {
        const int rb = 16 * rowg;
        f16x8 aS[4];
        #pragma unroll
        for (int kt = 0; kt < 4; kt++) {
            uint4 au = *(const uint4*)(&s_scr[(rb + lo) * 68 + 16 * kt + 4 * qd]);
            aS[kt] = __builtin_bit_cast(f16x8, au);
        }
        __syncthreads();
        {
            const int nt = wv;
            f32x4 acc = {0.f, 0.f, 0.f, 0.f};
            #pragma unroll
            for (int kt = 0; kt < 4; kt++) {
                uint4 bu = *(const uint4*)(pWvF + ((kt * 8 + nt) << 8) + (l << 2));
                acc = __builtin_amdgcn_mfma_f32_16x16x32_f16(aS[kt], __builtin_bit_cast(f16x8, bu), acc, 0, 0, 0);
            }
            #pragma unroll
            for (int r = 0; r < 4; r++)
                s_ctxh[(rb + 4 * qd + r) * 136 + 16 * nt + lo] = (_Float16)acc[r];
        }
    }
    __syncthreads();       // ctx fully ready

    // ---- stage 2: attn_vec = tanh(ctx @ proj + b) -> s_x cols 128..255 ----
    #pragma unroll
    for (int rowg = 0; rowg < 2; rowg++) {
        const int rb = 16 * rowg;
        f16x8 aC[4];
        #pragma unroll
        for (int kt = 0; kt < 4; kt++) {
            uint4 au = *(const uint4*)(&s_scr[(rb + lo) * 68 + 16 * kt + 4 * qd]);
            aC[kt] = __builtin_bit_cast(f16x8, au);
        }
        {
            const int nt = wv;
            f32x4 acc = {0.f, 0.f, 0.f, 0.f};
            #pragma unroll
            for (int kt = 0; kt < 4; kt++) {
                uint4 bu = *(const uint4*)(pPrF + ((kt * 8 + nt) << 8) + (l << 2));
                acc = __builtin_amdgcn_mfma_f32_16x16x32_f16(aC[kt], __builtin_bit_cast(f16x8, bu), acc, 0, 0, 0);
            }
            const float bn = proj_b[16 * nt + lo];
            #pragma unroll
            for (int r = 0; r < 4; r++)
                s_xh[(rb + 4 * qd + r) * 264 + 128 + 16 * nt + lo] = (_Float16)fast_tanh(acc[r] + bn);
        }
    }
    __syncthreads();       // x = [own_e || attn_vec] fully ready

    // ---- stage 3: h1 = lrelu(x @ H1 + b), in place over x; nt = 2wv+{0,1} ----
    {
        f16x8 aX[8];
        #pragma unroll
        for (int kt = 0; kt < 8; kt++) {
            uint4 au = *(const uint4*)(&s_x[lo * 132 + 16 * kt + 4 * qd]);
            aX[kt] = __builtin_bit_cast(f16x8, au);
        }
        __syncthreads();
        #pragma unroll
        for (int ni = 0; ni < 2; ni++) {
            const int nt = 2 * wv + ni;
            f32x4 acc = {0.f, 0.f, 0.f, 0.f};
            #pragma unroll
            for (int kt = 0; kt < 8; kt++) {
                uint4 bu = *(const uint4*)(pH1F + ((nt * 8 + kt) << 8) + (l << 2));
                acc = __builtin_amdgcn_mfma_f32_16x16x32_f16(aX[kt], __builtin_bit_cast(f16x8, bu), acc, 0, 0, 0);
            }
            const float bn = h1_b[16 * nt + lo];
            #pragma unroll
            for (int r = 0; r < 4; r++)
                s_xh[(4 * qd + r) * 264 + 16 * nt + lo] = (_Float16)lrelu(acc[r] + bn);
        }
        #pragma unroll
        for (int kt = 0; kt < 8; kt++) {
            uint4 au = *(const uint4*)(&s_x[(16 + lo) * 132 + 16 * kt + 4 * qd]);
            aX[kt] = __builtin_bit_cast(f16x8, au);
        }
        __syncthreads();
        #pragma unroll
        for (int ni = 0; ni < 2; ni++) {
            const int nt = 2 * wv + ni;
            f32x4 acc = {0.f, 0.f, 0.f, 0.f};
            #pragma unroll
            for (int kt = 0; kt < 8; kt++) {
                uint4 bu = *(const uint4*)(pH1F + ((nt * 8 + kt) << 8) + (l << 2));
                acc = __builtin_amdgcn_mfma_f32_16x16x32_f16(aX[kt], __builtin_bit_cast(f16x8, bu), acc, 0, 0, 0);
            }
            const float bn = h1_b[16 * nt + lo];
            #pragma unroll
            for (int r = 0; r < 4; r++)
                s_xh[(16 + 4 * qd + r) * 264 + 16 * nt + lo] = (_Float16)lrelu(acc[r] + bn);
        }
    }
    __syncthreads();       // h1 fully ready

    // ---- stage 4: out = lrelu(h1 @ H2 + b) @ out_W ; nt = 2wv+{0,1} ----
    #pragma unroll
    for (int rowg = 0; rowg < 2; rowg++) {
        const int rb = 16 * rowg;
        f16x8 aH[8];
        #pragma unroll
        for (int kt = 0; kt < 8; kt++) {
            uint4 au = *(const uint4*)(&s_x[(rb + lo) * 132 + 16 * kt + 4 * qd]);
            aH[kt] = __builtin_bit_cast(f16x8, au);
        }
        float o0[4] = {0.f, 0.f, 0.f, 0.f};
        float o1[4] = {0.f, 0.f, 0.f, 0.f};
        #pragma unroll
        for (int ni = 0; ni < 2; ni++) {
            const int nt = 2 * wv + ni;
            f32x4 acc = {0.f, 0.f, 0.f, 0.f};
            #pragma unroll
            for (int kt = 0; kt < 8; kt++) {
                uint4 bu = *(const uint4*)(pH2F + ((nt * 8 + kt) << 8) + (l << 2));
                acc = __builtin_amdgcn_mfma_f32_16x16x32_f16(aH[kt], __builtin_bit_cast(f16x8, bu), acc, 0, 0, 0);
            }
            const float bn = h2_b[16 * nt + lo];
            float2 w = *(const float2*)(out_W + (size_t)(16 * nt + lo) * OUTD);
            #pragma unroll
            for (int r = 0; r < 4; r++) {
                float v = lrelu(acc[r] + bn);
                o0[r] += v * w.x; o1[r] += v * w.y;
            }
        }
        #pragma unroll
        for (int r = 0; r < 4; r++) {
            #pragma unroll
            for (int w = 1; w <= 8; w <<= 1) {
                o0[r] += __shfl_xor(o0[r], w, 64);
                o1[r] += __shfl_xor(o1[r], w, 64);
            }
        }
        if (lo == 0) {
            #pragma unroll
            for (int r = 0; r < 4; r++) {
                s_red[wv][rb + 4 * qd + r][0] = o0[r];
                s_red[wv][rb + 4 * qd + r][1] = o1[r];
            }
        }
    }
    __syncthreads();
    if (tid < 64) {
        int r = tid >> 1, cmp = tid & 1;
        float s = out_b[cmp];
        #pragma unroll
        for (int w = 0; w < 8; w++) s += s_red[w][r][cmp];
        res[(row0 + r) * OUTD + cmp] = s;
    }
}

// Final copy: d_out's last writer — keep.
__global__ __launch_bounds__(256) void copy_out(const float* __restrict__ src,
                                               float* __restrict__ dst, int n4) {
    int i = blockIdx.x * 256 + threadIdx.x;
    if (i < n4) ((float4*)dst)[i] = ((const float4*)src)[i];
}

extern "C" void kernel_launch(void* const* d_in, const int* in_sizes, int n_in,
                              void* d_out, int out_size, void* d_ws, size_t ws_size,
                              hipStream_t stream) {
    const float* obs    = (const float*)d_in[0];
    const float* own_W  = (const float*)d_in[1];
    const float* own_b  = (const float*)d_in[2];
    const float* int_W  = (const float*)d_in[3];
    const float* int_b  = (const float*)d_in[4];
    const float* Wq     = (const float*)d_in[5];
    const float* Wk     = (const float*)d_in[6];
    const float* Wv     = (const float*)d_in[7];
    const float* v_att  = (const float*)d_in[8];
    const float* proj_W = (const float*)d_in[9];
    const float* proj_b = (const float*)d_in[10];
    const float* h1_W   = (const float*)d_in[11];
    const float* h1_b   = (const float*)d_in[12];
    const float* h2_W   = (const float*)d_in[13];
    const float* h2_b   = (const float*)d_in[14];
    const float* out_W  = (const float*)d_in[15];
    const float* out_b  = (const float*)d_in[16];

    const size_t res_bytes  = (size_t)BATCH * OUTD * sizeof(float);
    const size_t base_bytes = (size_t)UW_FULL * 4 + XBUF_U * 4 + res_bytes; // ~17 MB
    const int n4 = BATCH * OUTD / 4;

    if (ws_size >= base_bytes) {
        unsigned* pw   = (unsigned*)d_ws;
        unsigned* xbuf = pw + UW_FULL;
        float*    res  = (float*)(xbuf + XBUF_U);
        pack_full<<<(UW_FULL + 255) / 256, 256, 0, stream>>>(
            Wq, Wk, Wv, proj_W, int_W, int_b, h1_W, h2_W, pw);
        attn<<<BATCH / 4, 256, 0, stream>>>(
            obs, own_W, own_b, pw + UW_PIWF,
            pw + UW_PWKQ, v_att, xbuf);
        mlp8w<<<BATCH / 32, 512, 0, stream>>>(
            xbuf, pw + UW_PWVF, proj_b, pw + UW_PPRF,
            pw + UW_PH1F, h1_b, pw + UW_PH2F, h2_b, out_W, out_b, res);
        copy_out<<<(n4 + 255) / 256, 256, 0, stream>>>(res, (float*)d_out, n4);
    }
}

// Round 12
// 227.223 us; speedup vs baseline: 1.1967x; 1.1967x over previous
//
#include <hip/hip_runtime.h>
#include <hip/hip_bf16.h>
#include <math.h>

typedef _Float16 half2_t __attribute__((ext_vector_type(2)));
typedef _Float16 f16x8   __attribute__((ext_vector_type(8)));
typedef float    f32x4   __attribute__((ext_vector_type(4)));

constexpr int BATCH = 32768;
constexpr int NI   = 32;
constexpr int OWND = 3;
constexpr int INTD = 7;
constexpr int AD   = 128;
constexpr int HIDN = 256;
constexpr int OUTD = 2;
constexpr int OBSD = OWND + NI * INTD;  // 227
constexpr int IEPITCH = 68;             // uints (=136 halves)
constexpr float C2L2E = 2.885390081777927f;   // 2*log2(e)

__device__ __forceinline__ half2_t u2h(unsigned u) { return __builtin_bit_cast(half2_t, u); }
__device__ __forceinline__ unsigned packf(float a, float b) {
    half2_t h = { (_Float16)a, (_Float16)b };
    return __builtin_bit_cast(unsigned, h);
}
// slope<1 => lrelu(x) == max(x, 0.2x): 2 VALU (mul+max).
__device__ __forceinline__ float lrelu(float x) { return fmaxf(x, 0.2f * x); }
// hardware v_exp_f32 is 2^x; __builtin_amdgcn_exp2f is the portable spelling.
__device__ __forceinline__ float exp2fast(float x) { return __builtin_amdgcn_exp2f(x); }
// tanh via native exp2 + rcp.
__device__ __forceinline__ float fast_tanh(float x) {
    float e = exp2fast(x * C2L2E);
    return 1.0f - 2.0f * __builtin_amdgcn_rcpf(e + 1.0f);
}

// ===================== ws layout (uints) =====================
constexpr int UW_PWKQ = 0;        // [Wk;Wq] B-frags (f=kt*8+nt, kt<8; kt<4=Wk, kt>=4=Wq): 16384
constexpr int UW_PWVF = 16384;    // Wv B-frags (kt<4): 8192
constexpr int UW_PPRF = 24576;    // proj B-frags: 8192
constexpr int UW_PIWF = 32768;    // int_W K=32-padded B-frags (f=nt), bias fused at k=7: 2048
constexpr int UW_PH1F = 34816;    // h1 B-frags (f=nt*8+kt): 32768
constexpr int UW_PH2F = 67584;    // h2 B-frags: 32768
constexpr int UW_FULL = 100352;   // 392 KB
constexpr size_t XBUF_U = (size_t)BATCH * (HIDN / 2);  // 16 MB

// FUSION LEDGER (R10/R11): folding qgemm into attn was tried two ways —
// cross-wave shared q (+2 barriers, bank conflicts 2.6M) = 240us total;
// replicated-A q (+32 MFMA/wave on the critical chain) = 272us. Separate
// qgemm + 33MB qall round-trip (this file) = 238.6us — keep it separate.

__global__ __launch_bounds__(256) void pack_full(
    const float* __restrict__ Wq, const float* __restrict__ Wk,
    const float* __restrict__ Wv, const float* __restrict__ Pr,
    const float* __restrict__ IW, const float* __restrict__ IB,
    const float* __restrict__ H1, const float* __restrict__ H2,
    unsigned* __restrict__ dst)
{
    int u = blockIdx.x * 256 + threadIdx.x;
    if (u >= UW_FULL) return;
    if (u < 16384) {                       // [Wk;Wq] stacked B-frags (K=256)
        int f = u >> 8, kt = f >> 3, nt = f & 7;
        int idx = u & 255, lane = idx >> 2, w = idx & 3;
        int qd = lane >> 4, lo = lane & 15;
        const float* src = (kt < 4) ? Wk : Wq;
        int ktp = kt & 3;
        int r0 = 32 * ktp + 8 * qd + 2 * w, col = 16 * nt + lo;
        dst[u] = packf(src[r0 * 128 + col], src[(r0 + 1) * 128 + col]);
    } else if (u < 32768) {                // Wv / proj B-frags (128x128)
        const float* src = (u < 24576) ? Wv : Pr;
        int i = (u - 16384) & 8191;
        int f = i >> 8, kt = f >> 3, nt = f & 7;
        int idx = i & 255, lane = idx >> 2, w = idx & 3;
        int qd = lane >> 4, lo = lane & 15;
        int r0 = 32 * kt + 8 * qd + 2 * w, col = 16 * nt + lo;
        dst[u] = packf(src[r0 * 128 + col], src[(r0 + 1) * 128 + col]);
    } else if (u < 34816) {                // int_W (7x128) K=32-pad; k=7 row = int_b
        int i = u - 32768;
        int nt = i >> 8;
        int idx = i & 255, lane = idx >> 2, w = idx & 3;
        int qd = lane >> 4, lo = lane & 15;
        int r0 = 8 * qd + 2 * w, col = 16 * nt + lo;
        float v0 = (r0 < INTD) ? IW[r0 * 128 + col] : 0.f;       // r0 even, never ==7
        float v1 = (r0 + 1 < INTD) ? IW[(r0 + 1) * 128 + col]
                 : ((r0 + 1 == INTD) ? IB[col] : 0.f);
        dst[u] = packf(v0, v1);
    } else {                               // H1/H2 B-frags (256x256)
        int i = u - 34816;
        const float* src = (i < 32768) ? H1 : H2;
        i &= 32767;
        int f = i >> 8, nt = f >> 3, kt = f & 7;
        int idx = i & 255, lane = idx >> 2, w = idx & 3;
        int qd = lane >> 4, lo = lane & 15;
        int r0 = 32 * kt + 8 * qd + 2 * w, col = 16 * nt + lo;
        dst[u] = packf(src[r0 * 256 + col], src[(r0 + 1) * 256 + col]);
    }
}

// ---- qgemm v2: q = own_e @ Wq. FOUR waves per block, 16 rows per wave,
// wave-private LDS partitions, zero barriers. ----
__global__ __launch_bounds__(256) void qgemm(
    const float* __restrict__ obs, const float* __restrict__ own_W,
    const float* __restrict__ own_b, const unsigned* __restrict__ pWkqF,
    float* __restrict__ qall)
{
    const int wv = threadIdx.x >> 6;
    const int l  = threadIdx.x & 63;
    const int lo = l & 15, qd = l >> 4;
    const size_t row0 = (size_t)blockIdx.x * 64 + (size_t)wv * 16;

    __shared__ __align__(16) float    s_own[4][16][4];
    __shared__ __align__(16) unsigned s_oe[4][16 * 68];

    if (l < 16) {
        const float* orow = obs + (row0 + l) * OBSD;
        s_own[wv][l][0] = orow[0]; s_own[wv][l][1] = orow[1]; s_own[wv][l][2] = orow[2];
    }

    {   // own_e rows: lane (lo,qd) computes row lo, cols qd*32..qd*32+31
        const float x0 = s_own[wv][lo][0], x1 = s_own[wv][lo][1], x2 = s_own[wv][lo][2];
        #pragma unroll
        for (int jj = 0; jj < 8; jj++) {
            const int c4 = qd * 32 + jj * 4;
            float4 wb = *(const float4*)(own_b + c4);
            float4 w0 = *(const float4*)(own_W + 0 * AD + c4);
            float4 w1 = *(const float4*)(own_W + 1 * AD + c4);
            float4 w2 = *(const float4*)(own_W + 2 * AD + c4);
            float v0 = lrelu(wb.x + x0 * w0.x + x1 * w1.x + x2 * w2.x);
            float v1 = lrelu(wb.y + x0 * w0.y + x1 * w1.y + x2 * w2.y);
            float v2 = lrelu(wb.z + x0 * w0.z + x1 * w1.z + x2 * w2.z);
            float v3 = lrelu(wb.w + x0 * w0.w + x1 * w1.w + x2 * w2.w);
            s_oe[wv][lo * 68 + (c4 >> 1)]     = packf(v0, v1);
            s_oe[wv][lo * 68 + (c4 >> 1) + 1] = packf(v2, v3);
        }
    }

    f16x8 aE[4];
    #pragma unroll
    for (int kt = 0; kt < 4; kt++) {
        uint4 au = *(const uint4*)(&s_oe[wv][lo * 68 + 16 * kt + 4 * qd]);
        aE[kt] = __builtin_bit_cast(f16x8, au);
    }
    #pragma unroll
    for (int nt = 0; nt < 8; nt++) {
        f32x4 acc = {0.f, 0.f, 0.f, 0.f};
        #pragma unroll
        for (int kt = 0; kt < 4; kt++) {   // Wq lives at kt 4..7 of the stack
            uint4 bu = *(const uint4*)(pWkqF + (((kt + 4) * 8 + nt) << 8) + (l << 2));
            acc = __builtin_amdgcn_mfma_f32_16x16x32_f16(aE[kt], __builtin_bit_cast(f16x8, bu), acc, 0, 0, 0);
        }
        #pragma unroll
        for (int r = 0; r < 4; r++)
            qall[(row0 + 4 * qd + r) * AD + 16 * nt + lo] = acc[r];
    }
}

// ---- attention v7 (best measured: ~122-130us). Zero barriers, 4 rows per
// 4-wave block, q pre-computed by qgemm, bias-fused IWF, exp2 tanh chain,
// XOR-swizzled int_e LDS. Ledger of failed levers: occupancy x2 (R4 null),
// VALU cut (R6 null), weight-LDS (R8 -47us), q fusion both ways (R10/R11). ----
__global__ __launch_bounds__(256) void attn(
    const float* __restrict__ obs,
    const float* __restrict__ own_W, const float* __restrict__ own_b,
    const unsigned* __restrict__ pIWF,
    const unsigned* __restrict__ pWkqF, const float* __restrict__ v_att,
    const float* __restrict__ qall,
    unsigned* __restrict__ xbuf)
{
    const int wv = threadIdx.x >> 6;         // wave 0..3 -> row
    const int l  = threadIdx.x & 63;
    const int b  = blockIdx.x * 4 + wv;
    const int d0 = 2 * l;
    const int lo = l & 15, qd = l >> 4;

    __shared__ __align__(16) float    s_obs[4][OBSD];
    __shared__ __align__(16) unsigned s_ieb[4][NI * IEPITCH];  // int_e halves, swizzled
    __shared__ __align__(16) unsigned s_ownh[4][AD / 2];
    __shared__ __align__(16) float    s_sc[4][NI];             // scores, reused as alpha

    const float* orow = obs + (size_t)b * OBSD;
    for (int i = l; i < OBSD; i += 64) s_obs[wv][i] = orow[i];

    float oe0 = own_b[d0], oe1 = own_b[d0 + 1];
    #pragma unroll
    for (int j = 0; j < OWND; j++) {
        float x = s_obs[wv][j];
        oe0 += x * own_W[j * AD + d0];
        oe1 += x * own_W[j * AD + d0 + 1];
    }
    oe0 = lrelu(oe0); oe1 = lrelu(oe1);
    s_ownh[wv][l] = packf(oe0, oe1);

    int padf = 0;
    if (l < NI) {
        float su = 0.f;
        #pragma unroll
        for (int j = 0; j < INTD; j++) su += fabsf(s_obs[wv][OWND + l * INTD + j]);
        padf = (su < 1e-6f);
    }

    // per-lane q, pre-scaled by 2*log2e for the exp2-based tanh chain
    float qe[8];
    {
        const float* qrow = qall + (size_t)b * AD;
        #pragma unroll
        for (int nt = 0; nt < 8; nt++) qe[nt] = qrow[16 * nt + lo] * C2L2E;
    }

    // ---- int_e via MFMA; k=7 supplies 1.0 (bias row fused in IWF) ----
    f16x8 aInt[2];
    #pragma unroll
    for (int t = 0; t < 2; t++) {
        #pragma unroll
        for (int j = 0; j < 8; j++) {
            int k = 8 * qd + j;
            float v;
            if (k < INTD)       v = s_obs[wv][OWND + (16 * t + lo) * INTD + k];
            else if (k == INTD) v = 1.0f;
            else                v = 0.f;
            aInt[t][j] = (_Float16)v;
        }
    }
    // swizzled store: half-index col' = (16nt+lo) ^ (qd<<3)
    _Float16* s_ieh = (_Float16*)s_ieb[wv];
    #pragma unroll
    for (int nt = 0; nt < 8; nt++) {
        uint4 bu = *(const uint4*)(pIWF + (nt << 8) + (l << 2));
        f16x8 bf = __builtin_bit_cast(f16x8, bu);
        f32x4 z = {0.f, 0.f, 0.f, 0.f};
        f32x4 c0 = __builtin_amdgcn_mfma_f32_16x16x32_f16(aInt[0], bf, z, 0, 0, 0);
        f32x4 c1 = __builtin_amdgcn_mfma_f32_16x16x32_f16(aInt[1], bf, z, 0, 0, 0);
        const int cswz = (16 * nt + lo) ^ (qd << 3);
        #pragma unroll
        for (int r = 0; r < 4; r++) {
            s_ieh[(4 * qd + r) * 136 + cswz]      = (_Float16)lrelu(c0[r]);
            s_ieh[(16 + 4 * qd + r) * 136 + cswz] = (_Float16)lrelu(c1[r]);
        }
    }

    // ---- A-frags (swizzled read) ----
    const int slo = ((lo >> 2) & 3) << 2;
    f16x8 aIE[2][4];
    #pragma unroll
    for (int t = 0; t < 2; t++)
        #pragma unroll
        for (int kt = 0; kt < 4; kt++) {
            uint4 au = *(const uint4*)(&s_ieb[wv][(16 * t + lo) * IEPITCH + ((16 * kt + 4 * qd) ^ slo)]);
            aIE[t][kt] = __builtin_bit_cast(f16x8, au);
        }

    // ---- k MFMA + fused tanh-score partials ----
    float sA0[4] = {0.f, 0.f, 0.f, 0.f};
    float sA1[4] = {0.f, 0.f, 0.f, 0.f};
    float vsum = 0.f;
    #pragma unroll
    for (int nt = 0; nt < 8; nt++) {
        f32x4 acc0 = {0.f, 0.f, 0.f, 0.f};
        f32x4 acc1 = {0.f, 0.f, 0.f, 0.f};
        #pragma unroll
        for (int kt = 0; kt < 4; kt++) {
            uint4 bu = *(const uint4*)(pWkqF + ((kt * 8 + nt) << 8) + (l << 2));
            f16x8 bf = __builtin_bit_cast(f16x8, bu);
            acc0 = __builtin_amdgcn_mfma_f32_16x16x32_f16(aIE[0][kt], bf, acc0, 0, 0, 0);
            acc1 = __builtin_amdgcn_mfma_f32_16x16x32_f16(aIE[1][kt], bf, acc1, 0, 0, 0);
        }
        const float vc   = v_att[16 * nt + lo];
        const float n2vc = -2.0f * vc;
        vsum += vc;
        #pragma unroll
        for (int r = 0; r < 4; r++) {
            float t0 = exp2fast(fmaf(acc0[r], C2L2E, qe[nt]));
            sA0[r] = fmaf(n2vc, __builtin_amdgcn_rcpf(t0 + 1.0f), sA0[r]);
            float t1 = exp2fast(fmaf(acc1[r], C2L2E, qe[nt]));
            sA1[r] = fmaf(n2vc, __builtin_amdgcn_rcpf(t1 + 1.0f), sA1[r]);
        }
    }
    #pragma unroll
    for (int r = 0; r < 4; r++) { sA0[r] += vsum; sA1[r] += vsum; }
    #pragma unroll
    for (int r = 0; r < 4; r++) {
        #pragma unroll
        for (int w = 1; w <= 8; w <<= 1) {
            sA0[r] += __shfl_xor(sA0[r], w, 64);
            sA1[r] += __shfl_xor(sA1[r], w, 64);
        }
    }
    if (lo == 0) {
        #pragma unroll
        for (int r = 0; r < 4; r++) {
            s_sc[wv][4 * qd + r]      = sA0[r];
            s_sc[wv][16 + 4 * qd + r] = sA1[r];
        }
    }

    // ---- softmax ----
    {
        float sval = -INFINITY;
        if (l < NI && !padf) sval = s_sc[wv][l];
        float mm = sval;
        #pragma unroll
        for (int w = 1; w <= 16; w <<= 1) mm = fmaxf(mm, __shfl_xor(mm, w, 64));
        float e = (sval > -INFINITY) ? __expf(sval - mm) : 0.f;
        float dd = e;
        #pragma unroll
        for (int w = 1; w <= 16; w <<= 1) dd += __shfl_xor(dd, w, 64);
        if (l < NI) s_sc[wv][l] = (dd > 0.f) ? e * __builtin_amdgcn_rcpf(dd) : 0.f;  // nan_to_num
    }

    // ---- sv = alpha @ int_e ----
    float sv0 = 0.f, sv1 = 0.f;
    #pragma unroll
    for (int n = 0; n < NI; n++) {
        const int sn = ((n >> 2) & 3) << 2;
        half2_t ie = u2h(s_ieb[wv][n * IEPITCH + (l ^ sn)]);
        float a = s_sc[wv][n];
        sv0 += a * (float)ie.x; sv1 += a * (float)ie.y;
    }
    xbuf[(size_t)b * (HIDN / 2) + l]      = s_ownh[wv][l];
    xbuf[(size_t)b * (HIDN / 2) + 64 + l] = packf(sv0, sv1);
}

// ---- mlp8w: 32-row tiles, EIGHT waves (best so far) ----
__global__ __launch_bounds__(512) void mlp8w(
    const unsigned* __restrict__ xbuf,
    const unsigned* __restrict__ pWvF, const float* __restrict__ proj_b,
    const unsigned* __restrict__ pPrF,
    const unsigned* __restrict__ pH1F, const float* __restrict__ h1_b,
    const unsigned* __restrict__ pH2F, const float* __restrict__ h2_b,
    const float* __restrict__ out_W,   const float* __restrict__ out_b,
    float* __restrict__ res)
{
    const int tid = threadIdx.x;
    const int wv  = tid >> 6;          // wave 0..7
    const int l   = tid & 63;
    const int lo  = l & 15, qd = l >> 4;
    const size_t row0 = (size_t)blockIdx.x * 32;

    __shared__ __align__(16) unsigned s_x[32 * 132];    // own_e | attn_vec -> h1 (in place)
    __shared__ __align__(16) unsigned s_scr[32 * 68];   // sv -> ctx (in place)
    __shared__ __align__(16) float    s_red[8][32][2];

    #pragma unroll
    for (int it = 0; it < 2; it++) {
        int i = tid + it * 512;
        int r = i >> 5, cq = i & 31;
        uint4 u = *(const uint4*)(xbuf + (row0 + r) * 128 + cq * 4);
        if (cq < 16) *(uint4*)(&s_x[r * 132 + cq * 4]) = u;
        else         *(uint4*)(&s_scr[r * 68 + (cq - 16) * 4]) = u;
    }
    __syncthreads();

    _Float16* s_ctxh = (_Float16*)s_scr;
    _Float16* s_xh   = (_Float16*)s_x;

    // ---- stage 1: ctx = sv @ Wv ; wave owns nt = wv ----
    #pragma unroll
    for (int rowg = 0; rowg < 2; rowg++) {
        const int rb = 16 * rowg;
        f16x8 aS[4];
        #pragma unroll
        for (int kt = 0; kt < 4; kt++) {
            uint4 au = *(const uint4*)(&s_scr[(rb + lo) * 68 + 16 * kt + 4 * qd]);
            aS[kt] = __builtin_bit_cast(f16x8, au);
        }
        __syncthreads();
        {
            const int nt = wv;
            f32x4 acc = {0.f, 0.f, 0.f, 0.f};
            #pragma unroll
            for (int kt = 0; kt < 4; kt++) {
                uint4 bu = *(const uint4*)(pWvF + ((kt * 8 + nt) << 8) + (l << 2));
                acc = __builtin_amdgcn_mfma_f32_16x16x32_f16(aS[kt], __builtin_bit_cast(f16x8, bu), acc, 0, 0, 0);
            }
            #pragma unroll
            for (int r = 0; r < 4; r++)
                s_ctxh[(rb + 4 * qd + r) * 136 + 16 * nt + lo] = (_Float16)acc[r];
        }
    }
    __syncthreads();       // ctx fully ready

    // ---- stage 2: attn_vec = tanh(ctx @ proj + b) -> s_x cols 128..255 ----
    #pragma unroll
    for (int rowg = 0; rowg < 2; rowg++) {
        const int rb = 16 * rowg;
        f16x8 aC[4];
        #pragma unroll
        for (int kt = 0; kt < 4; kt++) {
            uint4 au = *(const uint4*)(&s_scr[(rb + lo) * 68 + 16 * kt + 4 * qd]);
            aC[kt] = __builtin_bit_cast(f16x8, au);
        }
        {
            const int nt = wv;
            f32x4 acc = {0.f, 0.f, 0.f, 0.f};
            #pragma unroll
            for (int kt = 0; kt < 4; kt++) {
                uint4 bu = *(const uint4*)(pPrF + ((kt * 8 + nt) << 8) + (l << 2));
                acc = __builtin_amdgcn_mfma_f32_16x16x32_f16(aC[kt], __builtin_bit_cast(f16x8, bu), acc, 0, 0, 0);
            }
            const float bn = proj_b[16 * nt + lo];
            #pragma unroll
            for (int r = 0; r < 4; r++)
                s_xh[(rb + 4 * qd + r) * 264 + 128 + 16 * nt + lo] = (_Float16)fast_tanh(acc[r] + bn);
        }
    }
    __syncthreads();       // x = [own_e || attn_vec] fully ready

    // ---- stage 3: h1 = lrelu(x @ H1 + b), in place over x; nt = 2wv+{0,1} ----
    {
        f16x8 aX[8];
        #pragma unroll
        for (int kt = 0; kt < 8; kt++) {
            uint4 au = *(const uint4*)(&s_x[lo * 132 + 16 * kt + 4 * qd]);
            aX[kt] = __builtin_bit_cast(f16x8, au);
        }
        __syncthreads();
        #pragma unroll
        for (int ni = 0; ni < 2; ni++) {
            const int nt = 2 * wv + ni;
            f32x4 acc = {0.f, 0.f, 0.f, 0.f};
            #pragma unroll
            for (int kt = 0; kt < 8; kt++) {
                uint4 bu = *(const uint4*)(pH1F + ((nt * 8 + kt) << 8) + (l << 2));
                acc = __builtin_amdgcn_mfma_f32_16x16x32_f16(aX[kt], __builtin_bit_cast(f16x8, bu), acc, 0, 0, 0);
            }
            const float bn = h1_b[16 * nt + lo];
            #pragma unroll
            for (int r = 0; r < 4; r++)
                s_xh[(4 * qd + r) * 264 + 16 * nt + lo] = (_Float16)lrelu(acc[r] + bn);
        }
        #pragma unroll
        for (int kt = 0; kt < 8; kt++) {
            uint4 au = *(const uint4*)(&s_x[(16 + lo) * 132 + 16 * kt + 4 * qd]);
            aX[kt] = __builtin_bit_cast(f16x8, au);
        }
        __syncthreads();
        #pragma unroll
        for (int ni = 0; ni < 2; ni++) {
            const int nt = 2 * wv + ni;
            f32x4 acc = {0.f, 0.f, 0.f, 0.f};
            #pragma unroll
            for (int kt = 0; kt < 8; kt++) {
                uint4 bu = *(const uint4*)(pH1F + ((nt * 8 + kt) << 8) + (l << 2));
                acc = __builtin_amdgcn_mfma_f32_16x16x32_f16(aX[kt], __builtin_bit_cast(f16x8, bu), acc, 0, 0, 0);
            }
            const float bn = h1_b[16 * nt + lo];
            #pragma unroll
            for (int r = 0; r < 4; r++)
                s_xh[(16 + 4 * qd + r) * 264 + 16 * nt + lo] = (_Float16)lrelu(acc[r] + bn);
        }
    }
    __syncthreads();       // h1 fully ready

    // ---- stage 4: out = lrelu(h1 @ H2 + b) @ out_W ; nt = 2wv+{0,1} ----
    #pragma unroll
    for (int rowg = 0; rowg < 2; rowg++) {
        const int rb = 16 * rowg;
        f16x8 aH[8];
        #pragma unroll
        for (int kt = 0; kt < 8; kt++) {
            uint4 au = *(const uint4*)(&s_x[(rb + lo) * 132 + 16 * kt + 4 * qd]);
            aH[kt] = __builtin_bit_cast(f16x8, au);
        }
        float o0[4] = {0.f, 0.f, 0.f, 0.f};
        float o1[4] = {0.f, 0.f, 0.f, 0.f};
        #pragma unroll
        for (int ni = 0; ni < 2; ni++) {
            const int nt = 2 * wv + ni;
            f32x4 acc = {0.f, 0.f, 0.f, 0.f};
            #pragma unroll
            for (int kt = 0; kt < 8; kt++) {
                uint4 bu = *(const uint4*)(pH2F + ((nt * 8 + kt) << 8) + (l << 2));
                acc = __builtin_amdgcn_mfma_f32_16x16x32_f16(aH[kt], __builtin_bit_cast(f16x8, bu), acc, 0, 0, 0);
            }
            const float bn = h2_b[16 * nt + lo];
            float2 w = *(const float2*)(out_W + (size_t)(16 * nt + lo) * OUTD);
            #pragma unroll
            for (int r = 0; r < 4; r++) {
                float v = lrelu(acc[r] + bn);
                o0[r] += v * w.x; o1[r] += v * w.y;
            }
        }
        #pragma unroll
        for (int r = 0; r < 4; r++) {
            #pragma unroll
            for (int w = 1; w <= 8; w <<= 1) {
                o0[r] += __shfl_xor(o0[r], w, 64);
                o1[r] += __shfl_xor(o1[r], w, 64);
            }
        }
        if (lo == 0) {
            #pragma unroll
            for (int r = 0; r < 4; r++) {
                s_red[wv][rb + 4 * qd + r][0] = o0[r];
                s_red[wv][rb + 4 * qd + r][1] = o1[r];
            }
        }
    }
    __syncthreads();
    if (tid < 64) {
        int r = tid >> 1, cmp = tid & 1;
        float s = out_b[cmp];
        #pragma unroll
        for (int w = 0; w < 8; w++) s += s_red[w][r][cmp];
        res[(row0 + r) * OUTD + cmp] = s;
    }
}

// Final copy: d_out's last writer — keep.
__global__ __launch_bounds__(256) void copy_out(const float* __restrict__ src,
                                               float* __restrict__ dst, int n4) {
    int i = blockIdx.x * 256 + threadIdx.x;
    if (i < n4) ((float4*)dst)[i] = ((const float4*)src)[i];
}

extern "C" void kernel_launch(void* const* d_in, const int* in_sizes, int n_in,
                              void* d_out, int out_size, void* d_ws, size_t ws_size,
                              hipStream_t stream) {
    const float* obs    = (const float*)d_in[0];
    const float* own_W  = (const float*)d_in[1];
    const float* own_b  = (const float*)d_in[2];
    const float* int_W  = (const float*)d_in[3];
    const float* int_b  = (const float*)d_in[4];
    const float* Wq     = (const float*)d_in[5];
    const float* Wk     = (const float*)d_in[6];
    const float* Wv     = (const float*)d_in[7];
    const float* v_att  = (const float*)d_in[8];
    const float* proj_W = (const float*)d_in[9];
    const float* proj_b = (const float*)d_in[10];
    const float* h1_W   = (const float*)d_in[11];
    const float* h1_b   = (const float*)d_in[12];
    const float* h2_W   = (const float*)d_in[13];
    const float* h2_b   = (const float*)d_in[14];
    const float* out_W  = (const float*)d_in[15];
    const float* out_b  = (const float*)d_in[16];

    const size_t res_bytes  = (size_t)BATCH * OUTD * sizeof(float);
    const size_t q_bytes    = (size_t)BATCH * AD * sizeof(float);          // 16.8 MB
    const size_t base_bytes = (size_t)UW_FULL * 4 + XBUF_U * 4 + res_bytes; // ~17 MB
    const int n4 = BATCH * OUTD / 4;

    if (ws_size >= base_bytes + q_bytes) {
        unsigned* pw   = (unsigned*)d_ws;
        unsigned* xbuf = pw + UW_FULL;
        float*    qall = (float*)(xbuf + XBUF_U);
        float*    res  = qall + (size_t)BATCH * AD;
        pack_full<<<(UW_FULL + 255) / 256, 256, 0, stream>>>(
            Wq, Wk, Wv, proj_W, int_W, int_b, h1_W, h2_W, pw);
        qgemm<<<BATCH / 64, 256, 0, stream>>>(obs, own_W, own_b, pw + UW_PWKQ, qall);
        attn<<<BATCH / 4, 256, 0, stream>>>(
            obs, own_W, own_b, pw + UW_PIWF,
            pw + UW_PWKQ, v_att, qall, xbuf);
        mlp8w<<<BATCH / 32, 512, 0, stream>>>(
            xbuf, pw + UW_PWVF, proj_b, pw + UW_PPRF,
            pw + UW_PH1F, h1_b, pw + UW_PH2F, h2_b, out_W, out_b, res);
        copy_out<<<(n4 + 255) / 256, 256, 0, stream>>>(res, (float*)d_out, n4);
    }
}